// Round 1
// baseline (672.635 us; speedup 1.0000x reference)
//
#include <hip/hip_runtime.h>

// ---------------------------------------------------------------------------
// BasketballGNN: 3-layer GCN, N=50000 nodes (128 feat), E=800000 edges.
//   norm: self-loops + symmetric 1/sqrt(deg) normalization
//   layer l: h = relu(scatter_add(norm * (h @ Wl)[src] -> dst) + bl)  (no relu l3)
// Strategy round 1 (correctness-first, fp32):
//   - degree via float atomicAdd, dis = rsqrt(deg)
//   - GEMM: 256-thr block, W staged in LDS, 8x4 (or 4x4) register tile
//     epilogue fuses self-loop agg init: agg[i] = h[i]*dis[i]^2 (+bias for L3)
//   - edge aggregation: 1 thread per (edge, channel), global float atomicAdd
// ---------------------------------------------------------------------------

__global__ __launch_bounds__(256) void fill1_kernel(float* __restrict__ p, int n) {
    int i = blockIdx.x * 256 + threadIdx.x;
    if (i < n) p[i] = 1.0f;  // self-loop contributes 1 to degree
}

__global__ __launch_bounds__(256) void deg_kernel(const int* __restrict__ dst,
                                                  float* __restrict__ deg, int E) {
    int e = blockIdx.x * 256 + threadIdx.x;
    if (e < E) atomicAdd(&deg[dst[e]], 1.0f);
}

__global__ __launch_bounds__(256) void rsqrt_kernel(float* __restrict__ p, int n) {
    int i = blockIdx.x * 256 + threadIdx.x;
    if (i < n) p[i] = rsqrtf(fmaxf(p[i], 1.0f));
}

// GEMM [N,K] @ [K,C] -> hout [N,C]; also writes aggout[i,c] = h*dis[i]^2 (+bias).
// NOTE: `in` and `aggout` may alias (layer 2 writes agg in-place over its input).
// They are deliberately NOT __restrict__; a __syncthreads() separates the read
// phase from the write phase.
template<int K, int C, int TR, bool AGG_BIAS>
__global__ __launch_bounds__(256) void gemm_agg_kernel(
    const float* in, const float* __restrict__ W, const float* __restrict__ dis,
    const float* __restrict__ bias, float* __restrict__ hout, float* aggout, int N)
{
    constexpr int TC = 4;
    constexpr int TX = C / TC;        // threads along columns
    constexpr int TY = 256 / TX;      // thread groups along rows
    constexpr int R  = TY * TR;       // rows per block
    __shared__ float Wl[K * C];

    const int tid = threadIdx.x;
    for (int i = tid; i < K * C; i += 256) Wl[i] = W[i];
    __syncthreads();

    const int tx = tid % TX, ty = tid / TX;
    const int row0 = blockIdx.x * R + ty * TR;
    const int cb = tx * TC;

    float acc[TR][4];
#pragma unroll
    for (int r = 0; r < TR; ++r) { acc[r][0] = acc[r][1] = acc[r][2] = acc[r][3] = 0.0f; }

    const bool full = (row0 + TR <= N);
    if (full) {
        const float* inp = in + (size_t)row0 * K;
        for (int k = 0; k < K; ++k) {
            const float4 w4 = *(const float4*)&Wl[k * C + cb];
#pragma unroll
            for (int r = 0; r < TR; ++r) {
                const float a = inp[r * K + k];
                acc[r][0] = fmaf(a, w4.x, acc[r][0]);
                acc[r][1] = fmaf(a, w4.y, acc[r][1]);
                acc[r][2] = fmaf(a, w4.z, acc[r][2]);
                acc[r][3] = fmaf(a, w4.w, acc[r][3]);
            }
        }
    } else {
        for (int k = 0; k < K; ++k) {
            const float4 w4 = *(const float4*)&Wl[k * C + cb];
#pragma unroll
            for (int r = 0; r < TR; ++r) {
                const int row = row0 + r;
                const float a = (row < N) ? in[(size_t)row * K + k] : 0.0f;
                acc[r][0] = fmaf(a, w4.x, acc[r][0]);
                acc[r][1] = fmaf(a, w4.y, acc[r][1]);
                acc[r][2] = fmaf(a, w4.z, acc[r][2]);
                acc[r][3] = fmaf(a, w4.w, acc[r][3]);
            }
        }
    }
    __syncthreads();  // all reads of `in` done before possibly-aliased agg writes

    float4 b4 = make_float4(0.f, 0.f, 0.f, 0.f);
    if (AGG_BIAS) b4 = *(const float4*)&bias[cb];

    if (full) {
#pragma unroll
        for (int r = 0; r < TR; ++r) {
            const int row = row0 + r;
            const float d = dis[row];
            const float s = d * d;
            float4 h4 = make_float4(acc[r][0], acc[r][1], acc[r][2], acc[r][3]);
            *(float4*)&hout[(size_t)row * C + cb] = h4;
            float4 g4 = make_float4(fmaf(h4.x, s, b4.x), fmaf(h4.y, s, b4.y),
                                    fmaf(h4.z, s, b4.z), fmaf(h4.w, s, b4.w));
            *(float4*)&aggout[(size_t)row * C + cb] = g4;
        }
    } else {
#pragma unroll
        for (int r = 0; r < TR; ++r) {
            const int row = row0 + r;
            if (row < N) {
                const float d = dis[row];
                const float s = d * d;
                float4 h4 = make_float4(acc[r][0], acc[r][1], acc[r][2], acc[r][3]);
                *(float4*)&hout[(size_t)row * C + cb] = h4;
                float4 g4 = make_float4(fmaf(h4.x, s, b4.x), fmaf(h4.y, s, b4.y),
                                        fmaf(h4.z, s, b4.z), fmaf(h4.w, s, b4.w));
                *(float4*)&aggout[(size_t)row * C + cb] = g4;
            }
        }
    }
}

// One thread per (edge, channel). C is a power of two (64 or 32).
template<int C>
__global__ __launch_bounds__(256) void edge_agg_kernel(
    const int* __restrict__ src, const int* __restrict__ dst,
    const float* __restrict__ dis, const float* __restrict__ h,
    float* __restrict__ agg, int E)
{
    const int g = blockIdx.x * 256 + threadIdx.x;
    const int e = g / C;
    const int c = g % C;
    if (e < E) {
        const int s = src[e];
        const int d = dst[e];
        const float w = dis[s] * dis[d];
        atomicAdd(&agg[(size_t)d * C + c], h[(size_t)s * C + c] * w);
    }
}

// out = relu(in + bias), 64 channels, float4-vectorized. n4 = N*64/4.
__global__ __launch_bounds__(256) void bias_relu_kernel(
    const float* __restrict__ in, const float* __restrict__ bias,
    float* __restrict__ out, int n4)
{
    int i = blockIdx.x * 256 + threadIdx.x;
    if (i < n4) {
        float4 v = ((const float4*)in)[i];
        float4 b = ((const float4*)bias)[i & 15];  // (i*4) % 64 channel group
        v.x = fmaxf(v.x + b.x, 0.0f);
        v.y = fmaxf(v.y + b.y, 0.0f);
        v.z = fmaxf(v.z + b.z, 0.0f);
        v.w = fmaxf(v.w + b.w, 0.0f);
        ((float4*)out)[i] = v;
    }
}

extern "C" void kernel_launch(void* const* d_in, const int* in_sizes, int n_in,
                              void* d_out, int out_size, void* d_ws, size_t ws_size,
                              hipStream_t stream) {
    const float* x   = (const float*)d_in[0];
    const int*  eidx = (const int*)d_in[1];
    const float* W1  = (const float*)d_in[2];
    const float* b1  = (const float*)d_in[3];
    const float* W2  = (const float*)d_in[4];
    const float* b2  = (const float*)d_in[5];
    const float* W3  = (const float*)d_in[6];
    const float* b3  = (const float*)d_in[7];
    float* out = (float*)d_out;

    const int N = in_sizes[0] / 128;
    const int E = in_sizes[1] / 2;
    const int* srcp = eidx;
    const int* dstp = eidx + E;

    char* ws = (char*)d_ws;
    float* dis = (float*)ws;                       // N floats
    float* A   = (float*)(ws + 262144);            // N*64 floats
    float* B   = A + (size_t)N * 64;               // N*64 floats

    const dim3 blk(256);

    // --- normalization ---
    fill1_kernel<<<dim3((N + 255) / 256), blk, 0, stream>>>(dis, N);
    deg_kernel<<<dim3((E + 255) / 256), blk, 0, stream>>>(dstp, dis, E);
    rsqrt_kernel<<<dim3((N + 255) / 256), blk, 0, stream>>>(dis, N);

    const int n4 = N * 16;  // N*64/4
    const unsigned agg64_blocks = (unsigned)(((long long)E * 64 + 255) / 256);
    const unsigned agg32_blocks = (unsigned)(((long long)E * 32 + 255) / 256);

    // --- layer 1: x[128] @ W1 -> 64, relu ---
    gemm_agg_kernel<128, 64, 8, false>
        <<<dim3((N + 127) / 128), blk, 0, stream>>>(x, W1, dis, nullptr, A, B, N);
    edge_agg_kernel<64><<<dim3(agg64_blocks), blk, 0, stream>>>(srcp, dstp, dis, A, B, E);
    bias_relu_kernel<<<dim3((n4 + 255) / 256), blk, 0, stream>>>(B, b1, A, n4);

    // --- layer 2: A[64] @ W2 -> 64, relu  (agg written in-place over A) ---
    gemm_agg_kernel<64, 64, 8, false>
        <<<dim3((N + 127) / 128), blk, 0, stream>>>(A, W2, dis, nullptr, B, A, N);
    edge_agg_kernel<64><<<dim3(agg64_blocks), blk, 0, stream>>>(srcp, dstp, dis, B, A, E);
    bias_relu_kernel<<<dim3((n4 + 255) / 256), blk, 0, stream>>>(A, b2, B, n4);

    // --- layer 3: B[64] @ W3 -> 32, +b3 (no relu), agg directly into d_out ---
    gemm_agg_kernel<64, 32, 4, true>
        <<<dim3((N + 127) / 128), blk, 0, stream>>>(B, W3, dis, b3, A, out, N);
    edge_agg_kernel<32><<<dim3(agg32_blocks), blk, 0, stream>>>(srcp, dstp, dis, A, out, E);
}

// Round 2
// 443.838 us; speedup vs baseline: 1.5155x; 1.5155x over previous
//
#include <hip/hip_runtime.h>

// ---------------------------------------------------------------------------
// BasketballGNN round 2: CSR-gather aggregation (no float atomics).
//   out[d] = dis[d] * ( h'[d] + sum_{s in N(d)} h'[s] ) + b,  h' = (h@W)*dis
//   - deg (int atomics) -> block scan -> offsets -> scatter src into csr
//   - GEMM: vectorized-K float4, W in LDS, epilogue scales by dis[row]
//   - agg: one wave per node, lane=channel, 256B coalesced row gathers
// ---------------------------------------------------------------------------

__global__ __launch_bounds__(256) void zero_deg_kernel(int* __restrict__ deg, int n) {
    int i = blockIdx.x * 256 + threadIdx.x;
    if (i < n) deg[i] = 0;
}

__global__ __launch_bounds__(256) void deg_count_kernel(const int* __restrict__ dst,
                                                        int* __restrict__ deg, int E) {
    int e = blockIdx.x * 256 + threadIdx.x;
    if (e < E) atomicAdd(&deg[dst[e]], 1);
}

// Pass 1: per-block inclusive scan of deg; off[i+1] = local inclusive; bsum[b] = block total.
__global__ __launch_bounds__(256) void scan1_kernel(const int* __restrict__ deg,
                                                    int* __restrict__ off,
                                                    int* __restrict__ bsum, int N) {
    __shared__ int s[256];
    const int t = threadIdx.x;
    const int i = blockIdx.x * 256 + t;
    s[t] = (i < N) ? deg[i] : 0;
    __syncthreads();
#pragma unroll
    for (int d = 1; d < 256; d <<= 1) {
        int add = (t >= d) ? s[t - d] : 0;
        __syncthreads();
        s[t] += add;
        __syncthreads();
    }
    if (i < N) off[i + 1] = s[t];
    if (t == 255) bsum[blockIdx.x] = s[255];
}

// Pass 2: single block exclusive-scans the block sums.
__global__ __launch_bounds__(256) void scan2_kernel(const int* __restrict__ bsum,
                                                    int* __restrict__ bo, int NB) {
    __shared__ int s[256];
    const int t = threadIdx.x;
    const int v = (t < NB) ? bsum[t] : 0;
    s[t] = v;
    __syncthreads();
#pragma unroll
    for (int d = 1; d < 256; d <<= 1) {
        int add = (t >= d) ? s[t - d] : 0;
        __syncthreads();
        s[t] += add;
        __syncthreads();
    }
    bo[t] = s[t] - v;  // exclusive
}

// Pass 3: add block offsets; also set off[0]=0 and compute dis = rsqrt(deg+1).
__global__ __launch_bounds__(256) void scan3_kernel(int* __restrict__ off,
                                                    const int* __restrict__ bo,
                                                    const int* __restrict__ deg,
                                                    float* __restrict__ dis, int N) {
    const int i = blockIdx.x * 256 + threadIdx.x;
    if (i < N) {
        off[i + 1] += bo[blockIdx.x];
        dis[i] = rsqrtf((float)deg[i] + 1.0f);
        if (i == 0) off[0] = 0;
    }
}

__global__ __launch_bounds__(256) void cursor_init_kernel(const int* __restrict__ off,
                                                          int* __restrict__ cursor, int N) {
    const int i = blockIdx.x * 256 + threadIdx.x;
    if (i < N) cursor[i] = off[i];
}

__global__ __launch_bounds__(256) void scatter_kernel(const int* __restrict__ src,
                                                      const int* __restrict__ dst,
                                                      int* __restrict__ cursor,
                                                      int* __restrict__ csr, int E) {
    const int e = blockIdx.x * 256 + threadIdx.x;
    if (e < E) {
        const int d = dst[e];
        const int pos = atomicAdd(&cursor[d], 1);
        csr[pos] = src[e];
    }
}

// GEMM: hp[i,:] = (in[i,:] @ W) * dis[i].   K%4==0, C%4==0.
template<int K, int C, int TR>
__global__ __launch_bounds__(256) void gemm_scale_kernel(
    const float* __restrict__ in, const float* __restrict__ W,
    const float* __restrict__ dis, float* __restrict__ hp, int N)
{
    constexpr int TC = 4;
    constexpr int TX = C / TC;
    constexpr int TY = 256 / TX;
    constexpr int R  = TY * TR;
    __shared__ float Wl[K * C];

    const int tid = threadIdx.x;
    for (int i = tid; i < K * C / 4; i += 256)
        ((float4*)Wl)[i] = ((const float4*)W)[i];
    __syncthreads();

    const int tx = tid % TX, ty = tid / TX;
    const int row0 = blockIdx.x * R + ty * TR;
    const int cb = tx * TC;

    float acc[TR][4];
#pragma unroll
    for (int r = 0; r < TR; ++r) acc[r][0] = acc[r][1] = acc[r][2] = acc[r][3] = 0.0f;

    if (row0 + TR <= N) {
        const float* inp = in + (size_t)row0 * K;
        for (int k4 = 0; k4 < K / 4; ++k4) {
            float4 w0 = *(const float4*)&Wl[(k4 * 4 + 0) * C + cb];
            float4 w1 = *(const float4*)&Wl[(k4 * 4 + 1) * C + cb];
            float4 w2 = *(const float4*)&Wl[(k4 * 4 + 2) * C + cb];
            float4 w3 = *(const float4*)&Wl[(k4 * 4 + 3) * C + cb];
#pragma unroll
            for (int r = 0; r < TR; ++r) {
                const float4 a = *(const float4*)&inp[r * K + k4 * 4];
                acc[r][0] = fmaf(a.x, w0.x, acc[r][0]);
                acc[r][1] = fmaf(a.x, w0.y, acc[r][1]);
                acc[r][2] = fmaf(a.x, w0.z, acc[r][2]);
                acc[r][3] = fmaf(a.x, w0.w, acc[r][3]);
                acc[r][0] = fmaf(a.y, w1.x, acc[r][0]);
                acc[r][1] = fmaf(a.y, w1.y, acc[r][1]);
                acc[r][2] = fmaf(a.y, w1.z, acc[r][2]);
                acc[r][3] = fmaf(a.y, w1.w, acc[r][3]);
                acc[r][0] = fmaf(a.z, w2.x, acc[r][0]);
                acc[r][1] = fmaf(a.z, w2.y, acc[r][1]);
                acc[r][2] = fmaf(a.z, w2.z, acc[r][2]);
                acc[r][3] = fmaf(a.z, w2.w, acc[r][3]);
                acc[r][0] = fmaf(a.w, w3.x, acc[r][0]);
                acc[r][1] = fmaf(a.w, w3.y, acc[r][1]);
                acc[r][2] = fmaf(a.w, w3.z, acc[r][2]);
                acc[r][3] = fmaf(a.w, w3.w, acc[r][3]);
            }
        }
#pragma unroll
        for (int r = 0; r < TR; ++r) {
            const int row = row0 + r;
            const float d = dis[row];
            float4 h4 = make_float4(acc[r][0] * d, acc[r][1] * d, acc[r][2] * d, acc[r][3] * d);
            *(float4*)&hp[(size_t)row * C + cb] = h4;
        }
    } else {
        for (int k = 0; k < K; ++k) {
            const float4 w4 = *(const float4*)&Wl[k * C + cb];
#pragma unroll
            for (int r = 0; r < TR; ++r) {
                const int row = row0 + r;
                const float a = (row < N) ? in[(size_t)row * K + k] : 0.0f;
                acc[r][0] = fmaf(a, w4.x, acc[r][0]);
                acc[r][1] = fmaf(a, w4.y, acc[r][1]);
                acc[r][2] = fmaf(a, w4.z, acc[r][2]);
                acc[r][3] = fmaf(a, w4.w, acc[r][3]);
            }
        }
#pragma unroll
        for (int r = 0; r < TR; ++r) {
            const int row = row0 + r;
            if (row < N) {
                const float d = dis[row];
                float4 h4 = make_float4(acc[r][0] * d, acc[r][1] * d, acc[r][2] * d, acc[r][3] * d);
                *(float4*)&hp[(size_t)row * C + cb] = h4;
            }
        }
    }
}

// Aggregation: (256/C) nodes per block, lane = channel. Coalesced row gathers.
template<int C, bool RELU>
__global__ __launch_bounds__(256) void agg_kernel(
    const int* __restrict__ off, const int* __restrict__ csr,
    const float* __restrict__ dis, const float* __restrict__ hp,
    const float* __restrict__ bias, float* __restrict__ out, int N)
{
    const int lane = threadIdx.x % C;
    const int node = blockIdx.x * (256 / C) + threadIdx.x / C;
    if (node >= N) return;
    const int s0 = off[node];
    const int s1 = off[node + 1];
    float sum = hp[(size_t)node * C + lane];          // self-loop term (h' = dis*h)
    for (int e = s0; e < s1; ++e) {
        const int s = csr[e];
        sum += hp[(size_t)s * C + lane];
    }
    float v = fmaf(dis[node], sum, bias[lane]);
    if (RELU) v = fmaxf(v, 0.0f);
    out[(size_t)node * C + lane] = v;
}

static inline size_t align_up(size_t x) { return (x + 255) & ~(size_t)255; }

extern "C" void kernel_launch(void* const* d_in, const int* in_sizes, int n_in,
                              void* d_out, int out_size, void* d_ws, size_t ws_size,
                              hipStream_t stream) {
    const float* x   = (const float*)d_in[0];
    const int*  eidx = (const int*)d_in[1];
    const float* W1  = (const float*)d_in[2];
    const float* b1  = (const float*)d_in[3];
    const float* W2  = (const float*)d_in[4];
    const float* b2  = (const float*)d_in[5];
    const float* W3  = (const float*)d_in[6];
    const float* b3  = (const float*)d_in[7];
    float* out = (float*)d_out;

    const int N = in_sizes[0] / 128;
    const int E = in_sizes[1] / 2;
    const int* srcp = eidx;
    const int* dstp = eidx + E;

    char* ws = (char*)d_ws;
    size_t o = 0;
    float* dis   = (float*)(ws + o); o = align_up(o + (size_t)N * 4);
    int* deg     = (int*)(ws + o);   o = align_up(o + (size_t)N * 4);
    int* off     = (int*)(ws + o);   o = align_up(o + (size_t)(N + 1) * 4);
    int* cursor  = (int*)(ws + o);   o = align_up(o + (size_t)N * 4);
    int* bsum    = (int*)(ws + o);   o = align_up(o + 256 * 4);
    int* bo      = (int*)(ws + o);   o = align_up(o + 256 * 4);
    int* csr     = (int*)(ws + o);   o = align_up(o + (size_t)E * 4);
    float* A     = (float*)(ws + o); o = align_up(o + (size_t)N * 64 * 4);
    float* B     = (float*)(ws + o); o = align_up(o + (size_t)N * 64 * 4);

    const dim3 blk(256);
    const int NB = (N + 255) / 256;

    // --- CSR build + normalization ---
    zero_deg_kernel<<<dim3(NB), blk, 0, stream>>>(deg, N);
    deg_count_kernel<<<dim3((E + 255) / 256), blk, 0, stream>>>(dstp, deg, E);
    scan1_kernel<<<dim3(NB), blk, 0, stream>>>(deg, off, bsum, N);
    scan2_kernel<<<dim3(1), blk, 0, stream>>>(bsum, bo, NB);
    scan3_kernel<<<dim3(NB), blk, 0, stream>>>(off, bo, deg, dis, N);
    cursor_init_kernel<<<dim3(NB), blk, 0, stream>>>(off, cursor, N);
    scatter_kernel<<<dim3((E + 255) / 256), blk, 0, stream>>>(srcp, dstp, cursor, csr, E);

    const int gemm_blocks = (N + 127) / 128;

    // --- layer 1: x[128] @ W1 -> h1' in A; agg -> B (relu + b1) ---
    gemm_scale_kernel<128, 64, 8><<<dim3(gemm_blocks), blk, 0, stream>>>(x, W1, dis, A, N);
    agg_kernel<64, true><<<dim3((N + 3) / 4), blk, 0, stream>>>(off, csr, dis, A, b1, B, N);

    // --- layer 2: B[64] @ W2 -> h2' in A; agg -> B (relu + b2) ---
    gemm_scale_kernel<64, 64, 8><<<dim3(gemm_blocks), blk, 0, stream>>>(B, W2, dis, A, N);
    agg_kernel<64, true><<<dim3((N + 3) / 4), blk, 0, stream>>>(off, csr, dis, A, b2, B, N);

    // --- layer 3: B[64] @ W3 -> h3' in A (N x 32); agg -> out (+b3, no relu) ---
    gemm_scale_kernel<64, 32, 4><<<dim3(gemm_blocks), blk, 0, stream>>>(B, W3, dis, A, N);
    agg_kernel<32, false><<<dim3((N + 7) / 8), blk, 0, stream>>>(off, csr, dis, A, b3, out, N);
}

// Round 3
// 330.318 us; speedup vs baseline: 2.0363x; 1.3437x over previous
//
#include <hip/hip_runtime.h>

// ---------------------------------------------------------------------------
// BasketballGNN round 3: latency-hiding CSR gather.
//   agg: one wave per node, wave split into G groups; each group gathers a
//   different edge row as float4/lane (full row per dwordx4), unroll x2 ->
//   2G outstanding gathers per wave. Cross-group shfl_xor reduction.
// ---------------------------------------------------------------------------

__global__ __launch_bounds__(256) void zero_deg_kernel(int* __restrict__ deg, int n) {
    int i = blockIdx.x * 256 + threadIdx.x;
    if (i < n) deg[i] = 0;
}

__global__ __launch_bounds__(256) void deg_count_kernel(const int* __restrict__ dst,
                                                        int* __restrict__ deg, int E) {
    int e = blockIdx.x * 256 + threadIdx.x;
    if (e < E) atomicAdd(&deg[dst[e]], 1);
}

__global__ __launch_bounds__(256) void scan1_kernel(const int* __restrict__ deg,
                                                    int* __restrict__ off,
                                                    int* __restrict__ bsum, int N) {
    __shared__ int s[256];
    const int t = threadIdx.x;
    const int i = blockIdx.x * 256 + t;
    s[t] = (i < N) ? deg[i] : 0;
    __syncthreads();
#pragma unroll
    for (int d = 1; d < 256; d <<= 1) {
        int add = (t >= d) ? s[t - d] : 0;
        __syncthreads();
        s[t] += add;
        __syncthreads();
    }
    if (i < N) off[i + 1] = s[t];
    if (t == 255) bsum[blockIdx.x] = s[255];
}

__global__ __launch_bounds__(256) void scan2_kernel(const int* __restrict__ bsum,
                                                    int* __restrict__ bo, int NB) {
    __shared__ int s[256];
    const int t = threadIdx.x;
    const int v = (t < NB) ? bsum[t] : 0;
    s[t] = v;
    __syncthreads();
#pragma unroll
    for (int d = 1; d < 256; d <<= 1) {
        int add = (t >= d) ? s[t - d] : 0;
        __syncthreads();
        s[t] += add;
        __syncthreads();
    }
    bo[t] = s[t] - v;  // exclusive
}

// off[i+1] += block offset; off[0]=0; dis = rsqrt(deg+1); cursor[i] = off[i] (excl.)
__global__ __launch_bounds__(256) void scan3_kernel(int* __restrict__ off,
                                                    const int* __restrict__ bo,
                                                    const int* __restrict__ deg,
                                                    float* __restrict__ dis,
                                                    int* __restrict__ cursor, int N) {
    const int i = blockIdx.x * 256 + threadIdx.x;
    if (i < N) {
        const int d = deg[i];
        const int inc = off[i + 1] + bo[blockIdx.x];
        off[i + 1] = inc;
        cursor[i] = inc - d;          // exclusive prefix = start offset
        dis[i] = rsqrtf((float)d + 1.0f);
        if (i == 0) off[0] = 0;
    }
}

__global__ __launch_bounds__(256) void scatter_kernel(const int* __restrict__ src,
                                                      const int* __restrict__ dst,
                                                      int* __restrict__ cursor,
                                                      int* __restrict__ csr, int E) {
    const int e = blockIdx.x * 256 + threadIdx.x;
    if (e < E) {
        const int d = dst[e];
        const int pos = atomicAdd(&cursor[d], 1);
        csr[pos] = src[e];
    }
}

// GEMM: hp[i,:] = (in[i,:] @ W) * dis[i].
template<int K, int C, int TR>
__global__ __launch_bounds__(256) void gemm_scale_kernel(
    const float* __restrict__ in, const float* __restrict__ W,
    const float* __restrict__ dis, float* __restrict__ hp, int N)
{
    constexpr int TC = 4;
    constexpr int TX = C / TC;
    constexpr int TY = 256 / TX;
    constexpr int R  = TY * TR;
    __shared__ float Wl[K * C];

    const int tid = threadIdx.x;
    for (int i = tid; i < K * C / 4; i += 256)
        ((float4*)Wl)[i] = ((const float4*)W)[i];
    __syncthreads();

    const int tx = tid % TX, ty = tid / TX;
    const int row0 = blockIdx.x * R + ty * TR;
    const int cb = tx * TC;

    float acc[TR][4];
#pragma unroll
    for (int r = 0; r < TR; ++r) acc[r][0] = acc[r][1] = acc[r][2] = acc[r][3] = 0.0f;

    if (row0 + TR <= N) {
        const float* inp = in + (size_t)row0 * K;
        for (int k4 = 0; k4 < K / 4; ++k4) {
            float4 w0 = *(const float4*)&Wl[(k4 * 4 + 0) * C + cb];
            float4 w1 = *(const float4*)&Wl[(k4 * 4 + 1) * C + cb];
            float4 w2 = *(const float4*)&Wl[(k4 * 4 + 2) * C + cb];
            float4 w3 = *(const float4*)&Wl[(k4 * 4 + 3) * C + cb];
#pragma unroll
            for (int r = 0; r < TR; ++r) {
                const float4 a = *(const float4*)&inp[r * K + k4 * 4];
                acc[r][0] = fmaf(a.x, w0.x, acc[r][0]);
                acc[r][1] = fmaf(a.x, w0.y, acc[r][1]);
                acc[r][2] = fmaf(a.x, w0.z, acc[r][2]);
                acc[r][3] = fmaf(a.x, w0.w, acc[r][3]);
                acc[r][0] = fmaf(a.y, w1.x, acc[r][0]);
                acc[r][1] = fmaf(a.y, w1.y, acc[r][1]);
                acc[r][2] = fmaf(a.y, w1.z, acc[r][2]);
                acc[r][3] = fmaf(a.y, w1.w, acc[r][3]);
                acc[r][0] = fmaf(a.z, w2.x, acc[r][0]);
                acc[r][1] = fmaf(a.z, w2.y, acc[r][1]);
                acc[r][2] = fmaf(a.z, w2.z, acc[r][2]);
                acc[r][3] = fmaf(a.z, w2.w, acc[r][3]);
                acc[r][0] = fmaf(a.w, w3.x, acc[r][0]);
                acc[r][1] = fmaf(a.w, w3.y, acc[r][1]);
                acc[r][2] = fmaf(a.w, w3.z, acc[r][2]);
                acc[r][3] = fmaf(a.w, w3.w, acc[r][3]);
            }
        }
#pragma unroll
        for (int r = 0; r < TR; ++r) {
            const int row = row0 + r;
            const float d = dis[row];
            float4 h4 = make_float4(acc[r][0] * d, acc[r][1] * d, acc[r][2] * d, acc[r][3] * d);
            *(float4*)&hp[(size_t)row * C + cb] = h4;
        }
    } else {
        for (int k = 0; k < K; ++k) {
            const float4 w4 = *(const float4*)&Wl[k * C + cb];
#pragma unroll
            for (int r = 0; r < TR; ++r) {
                const int row = row0 + r;
                const float a = (row < N) ? in[(size_t)row * K + k] : 0.0f;
                acc[r][0] = fmaf(a, w4.x, acc[r][0]);
                acc[r][1] = fmaf(a, w4.y, acc[r][1]);
                acc[r][2] = fmaf(a, w4.z, acc[r][2]);
                acc[r][3] = fmaf(a, w4.w, acc[r][3]);
            }
        }
#pragma unroll
        for (int r = 0; r < TR; ++r) {
            const int row = row0 + r;
            if (row < N) {
                const float d = dis[row];
                float4 h4 = make_float4(acc[r][0] * d, acc[r][1] * d, acc[r][2] * d, acc[r][3] * d);
                *(float4*)&hp[(size_t)row * C + cb] = h4;
            }
        }
    }
}

// Aggregation: one wave per node. Wave = G groups of (C/4) lanes; lane holds
// float4 (4 channels). Each group gathers a different edge row (full row per
// group per dwordx4), unrolled x2 -> 2G outstanding gathers per wave.
// G=4 for C=64, G=8 for C=32.
template<int C, bool RELU>
__global__ __launch_bounds__(256) void agg_kernel(
    const int* __restrict__ off, const int* __restrict__ csr,
    const float* __restrict__ dis, const float* __restrict__ hp,
    const float* __restrict__ bias, float* __restrict__ out, int N)
{
    constexpr int GL = C / 4;            // lanes per group (16 or 8)
    constexpr int G  = 64 / GL;          // groups per wave (4 or 8)
    const int wave = threadIdx.x >> 6;   // 0..3 (4 nodes per block)
    const int lane = threadIdx.x & 63;
    const int grp  = lane / GL;          // 0..G-1
    const int gl   = lane % GL;          // 0..GL-1
    const int node = blockIdx.x * 4 + wave;
    if (node >= N) return;

    const int s0 = off[node];
    const int s1 = off[node + 1];

    float4 acc = make_float4(0.f, 0.f, 0.f, 0.f);
    float4 acc2 = make_float4(0.f, 0.f, 0.f, 0.f);
    if (grp == 0) acc = *(const float4*)&hp[(size_t)node * C + gl * 4];  // self loop

    int e = s0 + grp;
    for (; e + G < s1; e += 2 * G) {
        const int sa = csr[e];
        const int sb = csr[e + G];
        const float4 va = *(const float4*)&hp[(size_t)sa * C + gl * 4];
        const float4 vb = *(const float4*)&hp[(size_t)sb * C + gl * 4];
        acc.x += va.x; acc.y += va.y; acc.z += va.z; acc.w += va.w;
        acc2.x += vb.x; acc2.y += vb.y; acc2.z += vb.z; acc2.w += vb.w;
    }
    if (e < s1) {
        const int sa = csr[e];
        const float4 va = *(const float4*)&hp[(size_t)sa * C + gl * 4];
        acc.x += va.x; acc.y += va.y; acc.z += va.z; acc.w += va.w;
    }
    acc.x += acc2.x; acc.y += acc2.y; acc.z += acc2.z; acc.w += acc2.w;

    // cross-group reduction: fold groups together (stride GL .. 32)
#pragma unroll
    for (int d = GL; d < 64; d <<= 1) {
        acc.x += __shfl_xor(acc.x, d);
        acc.y += __shfl_xor(acc.y, d);
        acc.z += __shfl_xor(acc.z, d);
        acc.w += __shfl_xor(acc.w, d);
    }

    if (grp == 0) {
        const float dn = dis[node];
        const float4 b4 = ((const float4*)bias)[gl];
        float4 v;
        v.x = fmaf(dn, acc.x, b4.x);
        v.y = fmaf(dn, acc.y, b4.y);
        v.z = fmaf(dn, acc.z, b4.z);
        v.w = fmaf(dn, acc.w, b4.w);
        if (RELU) {
            v.x = fmaxf(v.x, 0.f); v.y = fmaxf(v.y, 0.f);
            v.z = fmaxf(v.z, 0.f); v.w = fmaxf(v.w, 0.f);
        }
        *(float4*)&out[(size_t)node * C + gl * 4] = v;
    }
}

static inline size_t align_up(size_t x) { return (x + 255) & ~(size_t)255; }

extern "C" void kernel_launch(void* const* d_in, const int* in_sizes, int n_in,
                              void* d_out, int out_size, void* d_ws, size_t ws_size,
                              hipStream_t stream) {
    const float* x   = (const float*)d_in[0];
    const int*  eidx = (const int*)d_in[1];
    const float* W1  = (const float*)d_in[2];
    const float* b1  = (const float*)d_in[3];
    const float* W2  = (const float*)d_in[4];
    const float* b2  = (const float*)d_in[5];
    const float* W3  = (const float*)d_in[6];
    const float* b3  = (const float*)d_in[7];
    float* out = (float*)d_out;

    const int N = in_sizes[0] / 128;
    const int E = in_sizes[1] / 2;
    const int* srcp = eidx;
    const int* dstp = eidx + E;

    char* ws = (char*)d_ws;
    size_t o = 0;
    float* dis   = (float*)(ws + o); o = align_up(o + (size_t)N * 4);
    int* deg     = (int*)(ws + o);   o = align_up(o + (size_t)N * 4);
    int* off     = (int*)(ws + o);   o = align_up(o + (size_t)(N + 1) * 4);
    int* cursor  = (int*)(ws + o);   o = align_up(o + (size_t)N * 4);
    int* bsum    = (int*)(ws + o);   o = align_up(o + 256 * 4);
    int* bo      = (int*)(ws + o);   o = align_up(o + 256 * 4);
    int* csr     = (int*)(ws + o);   o = align_up(o + (size_t)E * 4);
    float* A     = (float*)(ws + o); o = align_up(o + (size_t)N * 64 * 4);
    float* B     = (float*)(ws + o); o = align_up(o + (size_t)N * 64 * 4);

    const dim3 blk(256);
    const int NB = (N + 255) / 256;

    // --- CSR build + normalization ---
    zero_deg_kernel<<<dim3(NB), blk, 0, stream>>>(deg, N);
    deg_count_kernel<<<dim3((E + 255) / 256), blk, 0, stream>>>(dstp, deg, E);
    scan1_kernel<<<dim3(NB), blk, 0, stream>>>(deg, off, bsum, N);
    scan2_kernel<<<dim3(1), blk, 0, stream>>>(bsum, bo, NB);
    scan3_kernel<<<dim3(NB), blk, 0, stream>>>(off, bo, deg, dis, cursor, N);
    scatter_kernel<<<dim3((E + 255) / 256), blk, 0, stream>>>(srcp, dstp, cursor, csr, E);

    const int gemm_blocks = (N + 127) / 128;
    const int agg_blocks = (N + 3) / 4;

    // --- layer 1: x[128] @ W1 -> h1' in A; agg -> B (relu + b1) ---
    gemm_scale_kernel<128, 64, 8><<<dim3(gemm_blocks), blk, 0, stream>>>(x, W1, dis, A, N);
    agg_kernel<64, true><<<dim3(agg_blocks), blk, 0, stream>>>(off, csr, dis, A, b1, B, N);

    // --- layer 2: B[64] @ W2 -> h2' in A; agg -> B (relu + b2) ---
    gemm_scale_kernel<64, 64, 8><<<dim3(gemm_blocks), blk, 0, stream>>>(B, W2, dis, A, N);
    agg_kernel<64, true><<<dim3(agg_blocks), blk, 0, stream>>>(off, csr, dis, A, b2, B, N);

    // --- layer 3: B[64] @ W3 -> h3' in A (N x 32); agg -> out (+b3, no relu) ---
    gemm_scale_kernel<64, 32, 4><<<dim3(gemm_blocks), blk, 0, stream>>>(B, W3, dis, A, N);
    agg_kernel<32, false><<<dim3(agg_blocks), blk, 0, stream>>>(off, csr, dis, A, b3, out, N);
}

// Round 4
// 267.264 us; speedup vs baseline: 2.5167x; 1.2359x over previous
//
#include <hip/hip_runtime.h>

// ---------------------------------------------------------------------------
// BasketballGNN round 4: atomic-free CSR build via 256-node buckets.
//   P1 histogram -> P2 scans -> P3 LDS counting-sort partition (coalesced
//   runs) -> P4 per-bucket LDS CSR build. No global atomics, no random
//   global stores. Edges packed: src(16b) | dst&255(8b) | bucket(8b).
//   gemm + gather-agg unchanged from round 3.
// ---------------------------------------------------------------------------

#define P3CAP 3200   // >= ceil(E / 256)
#define P4CAP 8192   // >= max edges per 256-node bucket (avg 4082 for E=800k)

// P1: per-block bucket histogram. grid=256 blocks.
__global__ __launch_bounds__(256) void part_hist_kernel(
    const int* __restrict__ dst, int* __restrict__ hist, int E, int nbuckets)
{
    __shared__ int lh[256];
    const int t = threadIdx.x;
    lh[t] = 0;
    __syncthreads();
    const int chunk = (E + gridDim.x - 1) / gridDim.x;
    const int e0 = blockIdx.x * chunk;
    const int e1 = min(E, e0 + chunk);
    for (int e = e0 + t; e < e1; e += 256)
        atomicAdd(&lh[dst[e] >> 8], 1);
    __syncthreads();
    if (t < nbuckets) hist[t * 256 + blockIdx.x] = lh[t];
}

// P2a: per-bucket scan of the 256 per-block counts -> exclusive offsets + total.
__global__ __launch_bounds__(256) void part_scan_kernel(
    int* __restrict__ hist, int* __restrict__ btot)
{
    __shared__ int s[256];
    const int t = threadIdx.x;
    const int b = blockIdx.x;
    const int v = hist[b * 256 + t];
    s[t] = v;
    __syncthreads();
#pragma unroll
    for (int d = 1; d < 256; d <<= 1) {
        int a = (t >= d) ? s[t - d] : 0;
        __syncthreads();
        s[t] += a;
        __syncthreads();
    }
    hist[b * 256 + t] = s[t] - v;  // exclusive within bucket
    if (t == 255) btot[b] = s[255];
}

// P2b: exclusive scan of bucket totals -> bucket bases (+ sentinel).
__global__ __launch_bounds__(256) void bucket_base_kernel(
    const int* __restrict__ btot, int* __restrict__ bbase, int nbuckets)
{
    __shared__ int s[256];
    const int t = threadIdx.x;
    const int v = (t < nbuckets) ? btot[t] : 0;
    s[t] = v;
    __syncthreads();
#pragma unroll
    for (int d = 1; d < 256; d <<= 1) {
        int a = (t >= d) ? s[t - d] : 0;
        __syncthreads();
        s[t] += a;
        __syncthreads();
    }
    if (t < nbuckets) bbase[t] = s[t] - v;
    if (t == nbuckets - 1) bbase[nbuckets] = s[t];
}

// P3: LDS counting-sort of each block's chunk by bucket, flush bucket-grouped
// (coalesced runs) to bedge. grid=256 blocks.
__global__ __launch_bounds__(256) void part_scatter_kernel(
    const int* __restrict__ src, const int* __restrict__ dst,
    const int* __restrict__ hist, const int* __restrict__ bbase,
    int* __restrict__ bedge, int E, int nbuckets)
{
    __shared__ int lh[256], gb[256], cur[256], s[256];
    __shared__ int stage[P3CAP];
    const int t = threadIdx.x;
    lh[t] = 0;
    __syncthreads();
    const int chunk = (E + gridDim.x - 1) / gridDim.x;
    const int e0 = blockIdx.x * chunk;
    const int e1 = min(E, e0 + chunk);
    for (int e = e0 + t; e < e1; e += 256)
        atomicAdd(&lh[dst[e] >> 8], 1);
    __syncthreads();
    const int v = lh[t];
    s[t] = v;
    __syncthreads();
#pragma unroll
    for (int d = 1; d < 256; d <<= 1) {
        int a = (t >= d) ? s[t - d] : 0;
        __syncthreads();
        s[t] += a;
        __syncthreads();
    }
    const int excl = s[t] - v;
    cur[t] = excl;
    if (t < nbuckets) gb[t] = bbase[t] + hist[t * 256 + blockIdx.x] - excl;
    __syncthreads();
    for (int e = e0 + t; e < e1; e += 256) {
        const int dv = dst[e];
        const int bucket = dv >> 8;
        const int r = atomicAdd(&cur[bucket], 1);
        stage[r] = (src[e] & 0xffff) | ((dv & 255) << 16) | (bucket << 24);
    }
    __syncthreads();
    const int cnt = e1 - e0;
    for (int i = t; i < cnt; i += 256) {
        const int p = stage[i];
        const int bucket = (int)((unsigned)p >> 24);
        bedge[gb[bucket] + i] = p;
    }
}

// P4: one block per bucket. LDS deg/scan/scatter -> coalesced csr slice,
// also emits off[] and dis[]. grid=nbuckets.
__global__ __launch_bounds__(256) void bucket_csr_kernel(
    const int* __restrict__ bedge, const int* __restrict__ bbase,
    int* __restrict__ csr, int* __restrict__ off, float* __restrict__ dis, int N)
{
    __shared__ int deg[256], cur[256], s[256];
    __shared__ int lcsr[P4CAP];
    const int t = threadIdx.x;
    const int b = blockIdx.x;
    const int e0 = bbase[b], e1 = bbase[b + 1];
    deg[t] = 0;
    __syncthreads();
    for (int e = e0 + t; e < e1; e += 256)
        atomicAdd(&deg[(bedge[e] >> 16) & 255], 1);
    __syncthreads();
    const int v = deg[t];
    s[t] = v;
    __syncthreads();
#pragma unroll
    for (int d = 1; d < 256; d <<= 1) {
        int a = (t >= d) ? s[t - d] : 0;
        __syncthreads();
        s[t] += a;
        __syncthreads();
    }
    cur[t] = s[t] - v;  // exclusive
    const int node = (b << 8) + t;
    if (node < N) {
        off[node + 1] = e0 + s[t];
        dis[node] = rsqrtf((float)v + 1.0f);
        if (node == 0) off[0] = 0;
    }
    __syncthreads();
    for (int e = e0 + t; e < e1; e += 256) {
        const int p = bedge[e];
        const int pos = atomicAdd(&cur[(p >> 16) & 255], 1);
        lcsr[pos] = p & 0xffff;
    }
    __syncthreads();
    for (int i = t; i < e1 - e0; i += 256)
        csr[e0 + i] = lcsr[i];
}

// GEMM: hp[i,:] = (in[i,:] @ W) * dis[i].
template<int K, int C, int TR>
__global__ __launch_bounds__(256) void gemm_scale_kernel(
    const float* __restrict__ in, const float* __restrict__ W,
    const float* __restrict__ dis, float* __restrict__ hp, int N)
{
    constexpr int TC = 4;
    constexpr int TX = C / TC;
    constexpr int TY = 256 / TX;
    constexpr int R  = TY * TR;
    __shared__ float Wl[K * C];

    const int tid = threadIdx.x;
    for (int i = tid; i < K * C / 4; i += 256)
        ((float4*)Wl)[i] = ((const float4*)W)[i];
    __syncthreads();

    const int tx = tid % TX, ty = tid / TX;
    const int row0 = blockIdx.x * R + ty * TR;
    const int cb = tx * TC;

    float acc[TR][4];
#pragma unroll
    for (int r = 0; r < TR; ++r) acc[r][0] = acc[r][1] = acc[r][2] = acc[r][3] = 0.0f;

    if (row0 + TR <= N) {
        const float* inp = in + (size_t)row0 * K;
        for (int k4 = 0; k4 < K / 4; ++k4) {
            float4 w0 = *(const float4*)&Wl[(k4 * 4 + 0) * C + cb];
            float4 w1 = *(const float4*)&Wl[(k4 * 4 + 1) * C + cb];
            float4 w2 = *(const float4*)&Wl[(k4 * 4 + 2) * C + cb];
            float4 w3 = *(const float4*)&Wl[(k4 * 4 + 3) * C + cb];
#pragma unroll
            for (int r = 0; r < TR; ++r) {
                const float4 a = *(const float4*)&inp[r * K + k4 * 4];
                acc[r][0] = fmaf(a.x, w0.x, acc[r][0]);
                acc[r][1] = fmaf(a.x, w0.y, acc[r][1]);
                acc[r][2] = fmaf(a.x, w0.z, acc[r][2]);
                acc[r][3] = fmaf(a.x, w0.w, acc[r][3]);
                acc[r][0] = fmaf(a.y, w1.x, acc[r][0]);
                acc[r][1] = fmaf(a.y, w1.y, acc[r][1]);
                acc[r][2] = fmaf(a.y, w1.z, acc[r][2]);
                acc[r][3] = fmaf(a.y, w1.w, acc[r][3]);
                acc[r][0] = fmaf(a.z, w2.x, acc[r][0]);
                acc[r][1] = fmaf(a.z, w2.y, acc[r][1]);
                acc[r][2] = fmaf(a.z, w2.z, acc[r][2]);
                acc[r][3] = fmaf(a.z, w2.w, acc[r][3]);
                acc[r][0] = fmaf(a.w, w3.x, acc[r][0]);
                acc[r][1] = fmaf(a.w, w3.y, acc[r][1]);
                acc[r][2] = fmaf(a.w, w3.z, acc[r][2]);
                acc[r][3] = fmaf(a.w, w3.w, acc[r][3]);
            }
        }
#pragma unroll
        for (int r = 0; r < TR; ++r) {
            const int row = row0 + r;
            const float d = dis[row];
            float4 h4 = make_float4(acc[r][0] * d, acc[r][1] * d, acc[r][2] * d, acc[r][3] * d);
            *(float4*)&hp[(size_t)row * C + cb] = h4;
        }
    } else {
        for (int k = 0; k < K; ++k) {
            const float4 w4 = *(const float4*)&Wl[k * C + cb];
#pragma unroll
            for (int r = 0; r < TR; ++r) {
                const int row = row0 + r;
                const float a = (row < N) ? in[(size_t)row * K + k] : 0.0f;
                acc[r][0] = fmaf(a, w4.x, acc[r][0]);
                acc[r][1] = fmaf(a, w4.y, acc[r][1]);
                acc[r][2] = fmaf(a, w4.z, acc[r][2]);
                acc[r][3] = fmaf(a, w4.w, acc[r][3]);
            }
        }
#pragma unroll
        for (int r = 0; r < TR; ++r) {
            const int row = row0 + r;
            if (row < N) {
                const float d = dis[row];
                float4 h4 = make_float4(acc[r][0] * d, acc[r][1] * d, acc[r][2] * d, acc[r][3] * d);
                *(float4*)&hp[(size_t)row * C + cb] = h4;
            }
        }
    }
}

// Aggregation: one wave per node, G groups gather different edge rows
// (float4/lane), unroll x2 -> 2G outstanding gathers. shfl_xor reduce.
template<int C, bool RELU>
__global__ __launch_bounds__(256) void agg_kernel(
    const int* __restrict__ off, const int* __restrict__ csr,
    const float* __restrict__ dis, const float* __restrict__ hp,
    const float* __restrict__ bias, float* __restrict__ out, int N)
{
    constexpr int GL = C / 4;            // lanes per group (16 or 8)
    constexpr int G  = 64 / GL;          // groups per wave (4 or 8)
    const int wave = threadIdx.x >> 6;
    const int lane = threadIdx.x & 63;
    const int grp  = lane / GL;
    const int gl   = lane % GL;
    const int node = blockIdx.x * 4 + wave;
    if (node >= N) return;

    const int s0 = off[node];
    const int s1 = off[node + 1];

    float4 acc = make_float4(0.f, 0.f, 0.f, 0.f);
    float4 acc2 = make_float4(0.f, 0.f, 0.f, 0.f);
    if (grp == 0) acc = *(const float4*)&hp[(size_t)node * C + gl * 4];  // self loop

    int e = s0 + grp;
    for (; e + G < s1; e += 2 * G) {
        const int sa = csr[e];
        const int sb = csr[e + G];
        const float4 va = *(const float4*)&hp[(size_t)sa * C + gl * 4];
        const float4 vb = *(const float4*)&hp[(size_t)sb * C + gl * 4];
        acc.x += va.x; acc.y += va.y; acc.z += va.z; acc.w += va.w;
        acc2.x += vb.x; acc2.y += vb.y; acc2.z += vb.z; acc2.w += vb.w;
    }
    if (e < s1) {
        const int sa = csr[e];
        const float4 va = *(const float4*)&hp[(size_t)sa * C + gl * 4];
        acc.x += va.x; acc.y += va.y; acc.z += va.z; acc.w += va.w;
    }
    acc.x += acc2.x; acc.y += acc2.y; acc.z += acc2.z; acc.w += acc2.w;

#pragma unroll
    for (int d = GL; d < 64; d <<= 1) {
        acc.x += __shfl_xor(acc.x, d);
        acc.y += __shfl_xor(acc.y, d);
        acc.z += __shfl_xor(acc.z, d);
        acc.w += __shfl_xor(acc.w, d);
    }

    if (grp == 0) {
        const float dn = dis[node];
        const float4 b4 = ((const float4*)bias)[gl];
        float4 v;
        v.x = fmaf(dn, acc.x, b4.x);
        v.y = fmaf(dn, acc.y, b4.y);
        v.z = fmaf(dn, acc.z, b4.z);
        v.w = fmaf(dn, acc.w, b4.w);
        if (RELU) {
            v.x = fmaxf(v.x, 0.f); v.y = fmaxf(v.y, 0.f);
            v.z = fmaxf(v.z, 0.f); v.w = fmaxf(v.w, 0.f);
        }
        *(float4*)&out[(size_t)node * C + gl * 4] = v;
    }
}

static inline size_t align_up(size_t x) { return (x + 255) & ~(size_t)255; }

extern "C" void kernel_launch(void* const* d_in, const int* in_sizes, int n_in,
                              void* d_out, int out_size, void* d_ws, size_t ws_size,
                              hipStream_t stream) {
    const float* x   = (const float*)d_in[0];
    const int*  eidx = (const int*)d_in[1];
    const float* W1  = (const float*)d_in[2];
    const float* b1  = (const float*)d_in[3];
    const float* W2  = (const float*)d_in[4];
    const float* b2  = (const float*)d_in[5];
    const float* W3  = (const float*)d_in[6];
    const float* b3  = (const float*)d_in[7];
    float* out = (float*)d_out;

    const int N = in_sizes[0] / 128;   // 50000 (< 65536 required for packing)
    const int E = in_sizes[1] / 2;     // 800000
    const int* srcp = eidx;
    const int* dstp = eidx + E;
    const int nbuckets = (N + 255) >> 8;   // 196

    char* ws = (char*)d_ws;
    size_t o = 0;
    float* dis   = (float*)(ws + o); o = align_up(o + (size_t)N * 4);
    int* off     = (int*)(ws + o);   o = align_up(o + (size_t)(N + 1) * 4);
    int* btot    = (int*)(ws + o);   o = align_up(o + 256 * 4);
    int* bbase   = (int*)(ws + o);   o = align_up(o + 257 * 4);
    int* hist    = (int*)(ws + o);   o = align_up(o + 256 * 256 * 4);
    int* bedge   = (int*)(ws + o);   o = align_up(o + (size_t)E * 4);
    int* csr     = (int*)(ws + o);   o = align_up(o + (size_t)E * 4);
    float* A     = (float*)(ws + o); o = align_up(o + (size_t)N * 64 * 4);
    float* B     = (float*)(ws + o); o = align_up(o + (size_t)N * 64 * 4);

    const dim3 blk(256);

    // --- CSR build (no global atomics) ---
    part_hist_kernel<<<dim3(256), blk, 0, stream>>>(dstp, hist, E, nbuckets);
    part_scan_kernel<<<dim3(nbuckets), blk, 0, stream>>>(hist, btot);
    bucket_base_kernel<<<dim3(1), blk, 0, stream>>>(btot, bbase, nbuckets);
    part_scatter_kernel<<<dim3(256), blk, 0, stream>>>(srcp, dstp, hist, bbase, bedge, E, nbuckets);
    bucket_csr_kernel<<<dim3(nbuckets), blk, 0, stream>>>(bedge, bbase, csr, off, dis, N);

    const int gemm_blocks = (N + 127) / 128;
    const int agg_blocks = (N + 3) / 4;

    // --- layer 1: x[128] @ W1 -> h1' in A; agg -> B (relu + b1) ---
    gemm_scale_kernel<128, 64, 8><<<dim3(gemm_blocks), blk, 0, stream>>>(x, W1, dis, A, N);
    agg_kernel<64, true><<<dim3(agg_blocks), blk, 0, stream>>>(off, csr, dis, A, b1, B, N);

    // --- layer 2: B[64] @ W2 -> h2' in A; agg -> B (relu + b2) ---
    gemm_scale_kernel<64, 64, 8><<<dim3(gemm_blocks), blk, 0, stream>>>(B, W2, dis, A, N);
    agg_kernel<64, true><<<dim3(agg_blocks), blk, 0, stream>>>(off, csr, dis, A, b2, B, N);

    // --- layer 3: B[64] @ W3 -> h3' in A (N x 32); agg -> out (+b3, no relu) ---
    gemm_scale_kernel<64, 32, 4><<<dim3(gemm_blocks), blk, 0, stream>>>(B, W3, dis, A, N);
    agg_kernel<32, false><<<dim3(agg_blocks), blk, 0, stream>>>(off, csr, dis, A, b3, out, N);
}

// Round 5
// 239.394 us; speedup vs baseline: 2.8097x; 1.1164x over previous
//
#include <hip/hip_runtime.h>

// ---------------------------------------------------------------------------
// BasketballGNN round 5: high-occupancy GEMM (TR=2 -> 1563 blocks, ~20
// waves/CU vs 6 before). CSR build (atomic-free, bucketed) and gather-agg
// unchanged from round 4.
// ---------------------------------------------------------------------------

#define P3CAP 3200   // >= ceil(E / 256)
#define P4CAP 8192   // >= max edges per 256-node bucket (avg 4082 for E=800k)

// P1: per-block bucket histogram. grid=256 blocks.
__global__ __launch_bounds__(256) void part_hist_kernel(
    const int* __restrict__ dst, int* __restrict__ hist, int E, int nbuckets)
{
    __shared__ int lh[256];
    const int t = threadIdx.x;
    lh[t] = 0;
    __syncthreads();
    const int chunk = (E + gridDim.x - 1) / gridDim.x;
    const int e0 = blockIdx.x * chunk;
    const int e1 = min(E, e0 + chunk);
    for (int e = e0 + t; e < e1; e += 256)
        atomicAdd(&lh[dst[e] >> 8], 1);
    __syncthreads();
    if (t < nbuckets) hist[t * 256 + blockIdx.x] = lh[t];
}

// P2a: per-bucket scan of the 256 per-block counts -> exclusive offsets + total.
__global__ __launch_bounds__(256) void part_scan_kernel(
    int* __restrict__ hist, int* __restrict__ btot)
{
    __shared__ int s[256];
    const int t = threadIdx.x;
    const int b = blockIdx.x;
    const int v = hist[b * 256 + t];
    s[t] = v;
    __syncthreads();
#pragma unroll
    for (int d = 1; d < 256; d <<= 1) {
        int a = (t >= d) ? s[t - d] : 0;
        __syncthreads();
        s[t] += a;
        __syncthreads();
    }
    hist[b * 256 + t] = s[t] - v;  // exclusive within bucket
    if (t == 255) btot[b] = s[255];
}

// P2b: exclusive scan of bucket totals -> bucket bases (+ sentinel).
__global__ __launch_bounds__(256) void bucket_base_kernel(
    const int* __restrict__ btot, int* __restrict__ bbase, int nbuckets)
{
    __shared__ int s[256];
    const int t = threadIdx.x;
    const int v = (t < nbuckets) ? btot[t] : 0;
    s[t] = v;
    __syncthreads();
#pragma unroll
    for (int d = 1; d < 256; d <<= 1) {
        int a = (t >= d) ? s[t - d] : 0;
        __syncthreads();
        s[t] += a;
        __syncthreads();
    }
    if (t < nbuckets) bbase[t] = s[t] - v;
    if (t == nbuckets - 1) bbase[nbuckets] = s[t];
}

// P3: LDS counting-sort of each block's chunk by bucket, flush bucket-grouped
// (coalesced runs) to bedge. grid=256 blocks.
__global__ __launch_bounds__(256) void part_scatter_kernel(
    const int* __restrict__ src, const int* __restrict__ dst,
    const int* __restrict__ hist, const int* __restrict__ bbase,
    int* __restrict__ bedge, int E, int nbuckets)
{
    __shared__ int lh[256], gb[256], cur[256], s[256];
    __shared__ int stage[P3CAP];
    const int t = threadIdx.x;
    lh[t] = 0;
    __syncthreads();
    const int chunk = (E + gridDim.x - 1) / gridDim.x;
    const int e0 = blockIdx.x * chunk;
    const int e1 = min(E, e0 + chunk);
    for (int e = e0 + t; e < e1; e += 256)
        atomicAdd(&lh[dst[e] >> 8], 1);
    __syncthreads();
    const int v = lh[t];
    s[t] = v;
    __syncthreads();
#pragma unroll
    for (int d = 1; d < 256; d <<= 1) {
        int a = (t >= d) ? s[t - d] : 0;
        __syncthreads();
        s[t] += a;
        __syncthreads();
    }
    const int excl = s[t] - v;
    cur[t] = excl;
    if (t < nbuckets) gb[t] = bbase[t] + hist[t * 256 + blockIdx.x] - excl;
    __syncthreads();
    for (int e = e0 + t; e < e1; e += 256) {
        const int dv = dst[e];
        const int bucket = dv >> 8;
        const int r = atomicAdd(&cur[bucket], 1);
        stage[r] = (src[e] & 0xffff) | ((dv & 255) << 16) | (bucket << 24);
    }
    __syncthreads();
    const int cnt = e1 - e0;
    for (int i = t; i < cnt; i += 256) {
        const int p = stage[i];
        const int bucket = (int)((unsigned)p >> 24);
        bedge[gb[bucket] + i] = p;
    }
}

// P4: one block per bucket. LDS deg/scan/scatter -> coalesced csr slice,
// also emits off[] and dis[]. grid=nbuckets.
__global__ __launch_bounds__(256) void bucket_csr_kernel(
    const int* __restrict__ bedge, const int* __restrict__ bbase,
    int* __restrict__ csr, int* __restrict__ off, float* __restrict__ dis, int N)
{
    __shared__ int deg[256], cur[256], s[256];
    __shared__ int lcsr[P4CAP];
    const int t = threadIdx.x;
    const int b = blockIdx.x;
    const int e0 = bbase[b], e1 = bbase[b + 1];
    deg[t] = 0;
    __syncthreads();
    for (int e = e0 + t; e < e1; e += 256)
        atomicAdd(&deg[(bedge[e] >> 16) & 255], 1);
    __syncthreads();
    const int v = deg[t];
    s[t] = v;
    __syncthreads();
#pragma unroll
    for (int d = 1; d < 256; d <<= 1) {
        int a = (t >= d) ? s[t - d] : 0;
        __syncthreads();
        s[t] += a;
        __syncthreads();
    }
    cur[t] = s[t] - v;  // exclusive
    const int node = (b << 8) + t;
    if (node < N) {
        off[node + 1] = e0 + s[t];
        dis[node] = rsqrtf((float)v + 1.0f);
        if (node == 0) off[0] = 0;
    }
    __syncthreads();
    for (int e = e0 + t; e < e1; e += 256) {
        const int p = bedge[e];
        const int pos = atomicAdd(&cur[(p >> 16) & 255], 1);
        lcsr[pos] = p & 0xffff;
    }
    __syncthreads();
    for (int i = t; i < e1 - e0; i += 256)
        csr[e0 + i] = lcsr[i];
}

// GEMM: hp[i,:] = (in[i,:] @ W) * dis[i].  TR=2: small row tile -> big grid.
template<int K, int C, int TR>
__global__ __launch_bounds__(256) void gemm_scale_kernel(
    const float* __restrict__ in, const float* __restrict__ W,
    const float* __restrict__ dis, float* __restrict__ hp, int N)
{
    constexpr int TC = 4;
    constexpr int TX = C / TC;
    constexpr int TY = 256 / TX;
    constexpr int R  = TY * TR;
    __shared__ float Wl[K * C];

    const int tid = threadIdx.x;
    for (int i = tid; i < K * C / 4; i += 256)
        ((float4*)Wl)[i] = ((const float4*)W)[i];
    __syncthreads();

    const int tx = tid % TX, ty = tid / TX;
    const int row0 = blockIdx.x * R + ty * TR;
    const int cb = tx * TC;

    float acc[TR][4];
#pragma unroll
    for (int r = 0; r < TR; ++r) acc[r][0] = acc[r][1] = acc[r][2] = acc[r][3] = 0.0f;

    if (row0 + TR <= N) {
        const float* inp = in + (size_t)row0 * K;
#pragma unroll 4
        for (int k4 = 0; k4 < K / 4; ++k4) {
            float4 w0 = *(const float4*)&Wl[(k4 * 4 + 0) * C + cb];
            float4 w1 = *(const float4*)&Wl[(k4 * 4 + 1) * C + cb];
            float4 w2 = *(const float4*)&Wl[(k4 * 4 + 2) * C + cb];
            float4 w3 = *(const float4*)&Wl[(k4 * 4 + 3) * C + cb];
#pragma unroll
            for (int r = 0; r < TR; ++r) {
                const float4 a = *(const float4*)&inp[r * K + k4 * 4];
                acc[r][0] = fmaf(a.x, w0.x, acc[r][0]);
                acc[r][1] = fmaf(a.x, w0.y, acc[r][1]);
                acc[r][2] = fmaf(a.x, w0.z, acc[r][2]);
                acc[r][3] = fmaf(a.x, w0.w, acc[r][3]);
                acc[r][0] = fmaf(a.y, w1.x, acc[r][0]);
                acc[r][1] = fmaf(a.y, w1.y, acc[r][1]);
                acc[r][2] = fmaf(a.y, w1.z, acc[r][2]);
                acc[r][3] = fmaf(a.y, w1.w, acc[r][3]);
                acc[r][0] = fmaf(a.z, w2.x, acc[r][0]);
                acc[r][1] = fmaf(a.z, w2.y, acc[r][1]);
                acc[r][2] = fmaf(a.z, w2.z, acc[r][2]);
                acc[r][3] = fmaf(a.z, w2.w, acc[r][3]);
                acc[r][0] = fmaf(a.w, w3.x, acc[r][0]);
                acc[r][1] = fmaf(a.w, w3.y, acc[r][1]);
                acc[r][2] = fmaf(a.w, w3.z, acc[r][2]);
                acc[r][3] = fmaf(a.w, w3.w, acc[r][3]);
            }
        }
#pragma unroll
        for (int r = 0; r < TR; ++r) {
            const int row = row0 + r;
            const float d = dis[row];
            float4 h4 = make_float4(acc[r][0] * d, acc[r][1] * d, acc[r][2] * d, acc[r][3] * d);
            *(float4*)&hp[(size_t)row * C + cb] = h4;
        }
    } else {
        for (int k = 0; k < K; ++k) {
            const float4 w4 = *(const float4*)&Wl[k * C + cb];
#pragma unroll
            for (int r = 0; r < TR; ++r) {
                const int row = row0 + r;
                const float a = (row < N) ? in[(size_t)row * K + k] : 0.0f;
                acc[r][0] = fmaf(a, w4.x, acc[r][0]);
                acc[r][1] = fmaf(a, w4.y, acc[r][1]);
                acc[r][2] = fmaf(a, w4.z, acc[r][2]);
                acc[r][3] = fmaf(a, w4.w, acc[r][3]);
            }
        }
#pragma unroll
        for (int r = 0; r < TR; ++r) {
            const int row = row0 + r;
            if (row < N) {
                const float d = dis[row];
                float4 h4 = make_float4(acc[r][0] * d, acc[r][1] * d, acc[r][2] * d, acc[r][3] * d);
                *(float4*)&hp[(size_t)row * C + cb] = h4;
            }
        }
    }
}

// Aggregation: one wave per node, G groups gather different edge rows
// (float4/lane), unroll x2 -> 2G outstanding gathers. shfl_xor reduce.
template<int C, bool RELU>
__global__ __launch_bounds__(256) void agg_kernel(
    const int* __restrict__ off, const int* __restrict__ csr,
    const float* __restrict__ dis, const float* __restrict__ hp,
    const float* __restrict__ bias, float* __restrict__ out, int N)
{
    constexpr int GL = C / 4;            // lanes per group (16 or 8)
    constexpr int G  = 64 / GL;          // groups per wave (4 or 8)
    const int wave = threadIdx.x >> 6;
    const int lane = threadIdx.x & 63;
    const int grp  = lane / GL;
    const int gl   = lane % GL;
    const int node = blockIdx.x * 4 + wave;
    if (node >= N) return;

    const int s0 = off[node];
    const int s1 = off[node + 1];

    float4 acc = make_float4(0.f, 0.f, 0.f, 0.f);
    float4 acc2 = make_float4(0.f, 0.f, 0.f, 0.f);
    if (grp == 0) acc = *(const float4*)&hp[(size_t)node * C + gl * 4];  // self loop

    int e = s0 + grp;
    for (; e + G < s1; e += 2 * G) {
        const int sa = csr[e];
        const int sb = csr[e + G];
        const float4 va = *(const float4*)&hp[(size_t)sa * C + gl * 4];
        const float4 vb = *(const float4*)&hp[(size_t)sb * C + gl * 4];
        acc.x += va.x; acc.y += va.y; acc.z += va.z; acc.w += va.w;
        acc2.x += vb.x; acc2.y += vb.y; acc2.z += vb.z; acc2.w += vb.w;
    }
    if (e < s1) {
        const int sa = csr[e];
        const float4 va = *(const float4*)&hp[(size_t)sa * C + gl * 4];
        acc.x += va.x; acc.y += va.y; acc.z += va.z; acc.w += va.w;
    }
    acc.x += acc2.x; acc.y += acc2.y; acc.z += acc2.z; acc.w += acc2.w;

#pragma unroll
    for (int d = GL; d < 64; d <<= 1) {
        acc.x += __shfl_xor(acc.x, d);
        acc.y += __shfl_xor(acc.y, d);
        acc.z += __shfl_xor(acc.z, d);
        acc.w += __shfl_xor(acc.w, d);
    }

    if (grp == 0) {
        const float dn = dis[node];
        const float4 b4 = ((const float4*)bias)[gl];
        float4 v;
        v.x = fmaf(dn, acc.x, b4.x);
        v.y = fmaf(dn, acc.y, b4.y);
        v.z = fmaf(dn, acc.z, b4.z);
        v.w = fmaf(dn, acc.w, b4.w);
        if (RELU) {
            v.x = fmaxf(v.x, 0.f); v.y = fmaxf(v.y, 0.f);
            v.z = fmaxf(v.z, 0.f); v.w = fmaxf(v.w, 0.f);
        }
        *(float4*)&out[(size_t)node * C + gl * 4] = v;
    }
}

static inline size_t align_up(size_t x) { return (x + 255) & ~(size_t)255; }

extern "C" void kernel_launch(void* const* d_in, const int* in_sizes, int n_in,
                              void* d_out, int out_size, void* d_ws, size_t ws_size,
                              hipStream_t stream) {
    const float* x   = (const float*)d_in[0];
    const int*  eidx = (const int*)d_in[1];
    const float* W1  = (const float*)d_in[2];
    const float* b1  = (const float*)d_in[3];
    const float* W2  = (const float*)d_in[4];
    const float* b2  = (const float*)d_in[5];
    const float* W3  = (const float*)d_in[6];
    const float* b3  = (const float*)d_in[7];
    float* out = (float*)d_out;

    const int N = in_sizes[0] / 128;   // 50000 (< 65536 required for packing)
    const int E = in_sizes[1] / 2;     // 800000
    const int* srcp = eidx;
    const int* dstp = eidx + E;
    const int nbuckets = (N + 255) >> 8;   // 196

    char* ws = (char*)d_ws;
    size_t o = 0;
    float* dis   = (float*)(ws + o); o = align_up(o + (size_t)N * 4);
    int* off     = (int*)(ws + o);   o = align_up(o + (size_t)(N + 1) * 4);
    int* btot    = (int*)(ws + o);   o = align_up(o + 256 * 4);
    int* bbase   = (int*)(ws + o);   o = align_up(o + 257 * 4);
    int* hist    = (int*)(ws + o);   o = align_up(o + 256 * 256 * 4);
    int* bedge   = (int*)(ws + o);   o = align_up(o + (size_t)E * 4);
    int* csr     = (int*)(ws + o);   o = align_up(o + (size_t)E * 4);
    float* A     = (float*)(ws + o); o = align_up(o + (size_t)N * 64 * 4);
    float* B     = (float*)(ws + o); o = align_up(o + (size_t)N * 64 * 4);

    const dim3 blk(256);

    // --- CSR build (no global atomics) ---
    part_hist_kernel<<<dim3(256), blk, 0, stream>>>(dstp, hist, E, nbuckets);
    part_scan_kernel<<<dim3(nbuckets), blk, 0, stream>>>(hist, btot);
    bucket_base_kernel<<<dim3(1), blk, 0, stream>>>(btot, bbase, nbuckets);
    part_scatter_kernel<<<dim3(256), blk, 0, stream>>>(srcp, dstp, hist, bbase, bedge, E, nbuckets);
    bucket_csr_kernel<<<dim3(nbuckets), blk, 0, stream>>>(bedge, bbase, csr, off, dis, N);

    const int agg_blocks = (N + 3) / 4;

    // rows per block: R = (256/(C/4)) * TR
    const int g1 = (N + 31) / 32;   // K=128,C=64,TR=2 -> R=32
    const int g2 = (N + 31) / 32;   // K=64, C=64,TR=2 -> R=32
    const int g3 = (N + 63) / 64;   // K=64, C=32,TR=2 -> R=64

    // --- layer 1: x[128] @ W1 -> h1' in A; agg -> B (relu + b1) ---
    gemm_scale_kernel<128, 64, 2><<<dim3(g1), blk, 0, stream>>>(x, W1, dis, A, N);
    agg_kernel<64, true><<<dim3(agg_blocks), blk, 0, stream>>>(off, csr, dis, A, b1, B, N);

    // --- layer 2: B[64] @ W2 -> h2' in A; agg -> B (relu + b2) ---
    gemm_scale_kernel<64, 64, 2><<<dim3(g2), blk, 0, stream>>>(B, W2, dis, A, N);
    agg_kernel<64, true><<<dim3(agg_blocks), blk, 0, stream>>>(off, csr, dis, A, b2, B, N);

    // --- layer 3: B[64] @ W3 -> h3' in A (N x 32); agg -> out (+b3, no relu) ---
    gemm_scale_kernel<64, 32, 2><<<dim3(g3), blk, 0, stream>>>(B, W3, dis, A, N);
    agg_kernel<32, false><<<dim3(agg_blocks), blk, 0, stream>>>(off, csr, dis, A, b3, out, N);
}

// Round 6
// 221.997 us; speedup vs baseline: 3.0299x; 1.0784x over previous
//
#include <hip/hip_runtime.h>
#include <hip/hip_fp16.h>

// ---------------------------------------------------------------------------
// BasketballGNN round 6: fp16 gather table.
//   h' = (h@W)*dis stored as fp16 (6.4 MB) -> agg gathers 128B rows (C=64),
//   8 groups/wave x unroll2 = 16 outstanding; accumulation fp32.
//   CSR build (atomic-free, bucketed) unchanged. GEMM TR=2 unchanged except
//   fp16 epilogue store.
// ---------------------------------------------------------------------------

#define P3CAP 3200   // >= ceil(E / 256)
#define P4CAP 8192   // >= max edges per 256-node bucket (avg 4082 for E=800k)

// P1: per-block bucket histogram. grid=256 blocks.
__global__ __launch_bounds__(256) void part_hist_kernel(
    const int* __restrict__ dst, int* __restrict__ hist, int E, int nbuckets)
{
    __shared__ int lh[256];
    const int t = threadIdx.x;
    lh[t] = 0;
    __syncthreads();
    const int chunk = (E + gridDim.x - 1) / gridDim.x;
    const int e0 = blockIdx.x * chunk;
    const int e1 = min(E, e0 + chunk);
    for (int e = e0 + t; e < e1; e += 256)
        atomicAdd(&lh[dst[e] >> 8], 1);
    __syncthreads();
    if (t < nbuckets) hist[t * 256 + blockIdx.x] = lh[t];
}

// P2a: per-bucket scan of the 256 per-block counts -> exclusive offsets + total.
__global__ __launch_bounds__(256) void part_scan_kernel(
    int* __restrict__ hist, int* __restrict__ btot)
{
    __shared__ int s[256];
    const int t = threadIdx.x;
    const int b = blockIdx.x;
    const int v = hist[b * 256 + t];
    s[t] = v;
    __syncthreads();
#pragma unroll
    for (int d = 1; d < 256; d <<= 1) {
        int a = (t >= d) ? s[t - d] : 0;
        __syncthreads();
        s[t] += a;
        __syncthreads();
    }
    hist[b * 256 + t] = s[t] - v;  // exclusive within bucket
    if (t == 255) btot[b] = s[255];
}

// P2b: exclusive scan of bucket totals -> bucket bases (+ sentinel).
__global__ __launch_bounds__(256) void bucket_base_kernel(
    const int* __restrict__ btot, int* __restrict__ bbase, int nbuckets)
{
    __shared__ int s[256];
    const int t = threadIdx.x;
    const int v = (t < nbuckets) ? btot[t] : 0;
    s[t] = v;
    __syncthreads();
#pragma unroll
    for (int d = 1; d < 256; d <<= 1) {
        int a = (t >= d) ? s[t - d] : 0;
        __syncthreads();
        s[t] += a;
        __syncthreads();
    }
    if (t < nbuckets) bbase[t] = s[t] - v;
    if (t == nbuckets - 1) bbase[nbuckets] = s[t];
}

// P3: LDS counting-sort of each block's chunk by bucket, flush bucket-grouped
// (coalesced runs) to bedge. grid=256 blocks.
__global__ __launch_bounds__(256) void part_scatter_kernel(
    const int* __restrict__ src, const int* __restrict__ dst,
    const int* __restrict__ hist, const int* __restrict__ bbase,
    int* __restrict__ bedge, int E, int nbuckets)
{
    __shared__ int lh[256], gb[256], cur[256], s[256];
    __shared__ int stage[P3CAP];
    const int t = threadIdx.x;
    lh[t] = 0;
    __syncthreads();
    const int chunk = (E + gridDim.x - 1) / gridDim.x;
    const int e0 = blockIdx.x * chunk;
    const int e1 = min(E, e0 + chunk);
    for (int e = e0 + t; e < e1; e += 256)
        atomicAdd(&lh[dst[e] >> 8], 1);
    __syncthreads();
    const int v = lh[t];
    s[t] = v;
    __syncthreads();
#pragma unroll
    for (int d = 1; d < 256; d <<= 1) {
        int a = (t >= d) ? s[t - d] : 0;
        __syncthreads();
        s[t] += a;
        __syncthreads();
    }
    const int excl = s[t] - v;
    cur[t] = excl;
    if (t < nbuckets) gb[t] = bbase[t] + hist[t * 256 + blockIdx.x] - excl;
    __syncthreads();
    for (int e = e0 + t; e < e1; e += 256) {
        const int dv = dst[e];
        const int bucket = dv >> 8;
        const int r = atomicAdd(&cur[bucket], 1);
        stage[r] = (src[e] & 0xffff) | ((dv & 255) << 16) | (bucket << 24);
    }
    __syncthreads();
    const int cnt = e1 - e0;
    for (int i = t; i < cnt; i += 256) {
        const int p = stage[i];
        const int bucket = (int)((unsigned)p >> 24);
        bedge[gb[bucket] + i] = p;
    }
}

// P4: one block per bucket. LDS deg/scan/scatter -> coalesced csr slice,
// also emits off[] and dis[]. grid=nbuckets.
__global__ __launch_bounds__(256) void bucket_csr_kernel(
    const int* __restrict__ bedge, const int* __restrict__ bbase,
    int* __restrict__ csr, int* __restrict__ off, float* __restrict__ dis, int N)
{
    __shared__ int deg[256], cur[256], s[256];
    __shared__ int lcsr[P4CAP];
    const int t = threadIdx.x;
    const int b = blockIdx.x;
    const int e0 = bbase[b], e1 = bbase[b + 1];
    deg[t] = 0;
    __syncthreads();
    for (int e = e0 + t; e < e1; e += 256)
        atomicAdd(&deg[(bedge[e] >> 16) & 255], 1);
    __syncthreads();
    const int v = deg[t];
    s[t] = v;
    __syncthreads();
#pragma unroll
    for (int d = 1; d < 256; d <<= 1) {
        int a = (t >= d) ? s[t - d] : 0;
        __syncthreads();
        s[t] += a;
        __syncthreads();
    }
    cur[t] = s[t] - v;  // exclusive
    const int node = (b << 8) + t;
    if (node < N) {
        off[node + 1] = e0 + s[t];
        dis[node] = rsqrtf((float)v + 1.0f);
        if (node == 0) off[0] = 0;
    }
    __syncthreads();
    for (int e = e0 + t; e < e1; e += 256) {
        const int p = bedge[e];
        const int pos = atomicAdd(&cur[(p >> 16) & 255], 1);
        lcsr[pos] = p & 0xffff;
    }
    __syncthreads();
    for (int i = t; i < e1 - e0; i += 256)
        csr[e0 + i] = lcsr[i];
}

// GEMM: hp[i,:] = fp16( (in[i,:] @ W) * dis[i] ).  TR=2 high-occupancy tile.
template<int K, int C, int TR>
__global__ __launch_bounds__(256) void gemm_scale_kernel(
    const float* __restrict__ in, const float* __restrict__ W,
    const float* __restrict__ dis, __half* __restrict__ hp, int N)
{
    constexpr int TC = 4;
    constexpr int TX = C / TC;
    constexpr int TY = 256 / TX;
    constexpr int R  = TY * TR;
    __shared__ float Wl[K * C];

    const int tid = threadIdx.x;
    for (int i = tid; i < K * C / 4; i += 256)
        ((float4*)Wl)[i] = ((const float4*)W)[i];
    __syncthreads();

    const int tx = tid % TX, ty = tid / TX;
    const int row0 = blockIdx.x * R + ty * TR;
    const int cb = tx * TC;

    float acc[TR][4];
#pragma unroll
    for (int r = 0; r < TR; ++r) acc[r][0] = acc[r][1] = acc[r][2] = acc[r][3] = 0.0f;

    auto store_row = [&](int row, int r) {
        const float d = dis[row];
        __half2 h0 = __float22half2_rn(make_float2(acc[r][0] * d, acc[r][1] * d));
        __half2 h1 = __float22half2_rn(make_float2(acc[r][2] * d, acc[r][3] * d));
        uint2 u;
        u.x = *(unsigned*)&h0;
        u.y = *(unsigned*)&h1;
        *(uint2*)&hp[(size_t)row * C + cb] = u;   // 8B aligned (cb%4==0)
    };

    if (row0 + TR <= N) {
        const float* inp = in + (size_t)row0 * K;
#pragma unroll 4
        for (int k4 = 0; k4 < K / 4; ++k4) {
            float4 w0 = *(const float4*)&Wl[(k4 * 4 + 0) * C + cb];
            float4 w1 = *(const float4*)&Wl[(k4 * 4 + 1) * C + cb];
            float4 w2 = *(const float4*)&Wl[(k4 * 4 + 2) * C + cb];
            float4 w3 = *(const float4*)&Wl[(k4 * 4 + 3) * C + cb];
#pragma unroll
            for (int r = 0; r < TR; ++r) {
                const float4 a = *(const float4*)&inp[r * K + k4 * 4];
                acc[r][0] = fmaf(a.x, w0.x, acc[r][0]);
                acc[r][1] = fmaf(a.x, w0.y, acc[r][1]);
                acc[r][2] = fmaf(a.x, w0.z, acc[r][2]);
                acc[r][3] = fmaf(a.x, w0.w, acc[r][3]);
                acc[r][0] = fmaf(a.y, w1.x, acc[r][0]);
                acc[r][1] = fmaf(a.y, w1.y, acc[r][1]);
                acc[r][2] = fmaf(a.y, w1.z, acc[r][2]);
                acc[r][3] = fmaf(a.y, w1.w, acc[r][3]);
                acc[r][0] = fmaf(a.z, w2.x, acc[r][0]);
                acc[r][1] = fmaf(a.z, w2.y, acc[r][1]);
                acc[r][2] = fmaf(a.z, w2.z, acc[r][2]);
                acc[r][3] = fmaf(a.z, w2.w, acc[r][3]);
                acc[r][0] = fmaf(a.w, w3.x, acc[r][0]);
                acc[r][1] = fmaf(a.w, w3.y, acc[r][1]);
                acc[r][2] = fmaf(a.w, w3.z, acc[r][2]);
                acc[r][3] = fmaf(a.w, w3.w, acc[r][3]);
            }
        }
#pragma unroll
        for (int r = 0; r < TR; ++r) store_row(row0 + r, r);
    } else {
        for (int k = 0; k < K; ++k) {
            const float4 w4 = *(const float4*)&Wl[k * C + cb];
#pragma unroll
            for (int r = 0; r < TR; ++r) {
                const int row = row0 + r;
                const float a = (row < N) ? in[(size_t)row * K + k] : 0.0f;
                acc[r][0] = fmaf(a, w4.x, acc[r][0]);
                acc[r][1] = fmaf(a, w4.y, acc[r][1]);
                acc[r][2] = fmaf(a, w4.z, acc[r][2]);
                acc[r][3] = fmaf(a, w4.w, acc[r][3]);
            }
        }
#pragma unroll
        for (int r = 0; r < TR; ++r)
            if (row0 + r < N) store_row(row0 + r, r);
    }
}

// Aggregation over fp16 gather table. One wave per node; G = 64/(C/8) groups,
// each gathers a different edge row (16B/lane = 8 fp16 ch), unroll x2 ->
// 2G outstanding (16 for C=64, 32 for C=32). fp32 accumulate + shfl reduce.
template<int C, bool RELU>
__global__ __launch_bounds__(256) void agg_kernel(
    const int* __restrict__ off, const int* __restrict__ csr,
    const float* __restrict__ dis, const __half* __restrict__ hp,
    const float* __restrict__ bias, float* __restrict__ out, int N)
{
    constexpr int GL = C / 8;            // lanes per group (8 or 4)
    constexpr int G  = 64 / GL;          // groups per wave (8 or 16)
    const int wave = threadIdx.x >> 6;
    const int lane = threadIdx.x & 63;
    const int grp  = lane / GL;
    const int gl   = lane % GL;
    const int node = blockIdx.x * 4 + wave;
    if (node >= N) return;

    const int s0 = off[node];
    const int s1 = off[node + 1];

    float acc[8]  = {0, 0, 0, 0, 0, 0, 0, 0};
    float acc2[8] = {0, 0, 0, 0, 0, 0, 0, 0};

    auto accum = [](float4 v, float* a) {
        const __half2* h2 = (const __half2*)&v;
#pragma unroll
        for (int j = 0; j < 4; ++j) {
            const float2 p = __half22float2(h2[j]);
            a[2 * j]     += p.x;
            a[2 * j + 1] += p.y;
        }
    };

    if (grp == 0) {
        const float4 v = *(const float4*)&hp[(size_t)node * C + gl * 8];  // self loop
        accum(v, acc);
    }

    int e = s0 + grp;
    for (; e + G < s1; e += 2 * G) {
        const int sa = csr[e];
        const int sb = csr[e + G];
        const float4 va = *(const float4*)&hp[(size_t)sa * C + gl * 8];
        const float4 vb = *(const float4*)&hp[(size_t)sb * C + gl * 8];
        accum(va, acc);
        accum(vb, acc2);
    }
    if (e < s1) {
        const int sa = csr[e];
        const float4 va = *(const float4*)&hp[(size_t)sa * C + gl * 8];
        accum(va, acc);
    }
#pragma unroll
    for (int j = 0; j < 8; ++j) acc[j] += acc2[j];

#pragma unroll
    for (int d = GL; d < 64; d <<= 1) {
#pragma unroll
        for (int j = 0; j < 8; ++j) acc[j] += __shfl_xor(acc[j], d);
    }

    if (grp == 0) {
        const float dn = dis[node];
        float v[8];
#pragma unroll
        for (int j = 0; j < 8; ++j) {
            v[j] = fmaf(dn, acc[j], bias[gl * 8 + j]);
            if (RELU) v[j] = fmaxf(v[j], 0.f);
        }
        *(float4*)&out[(size_t)node * C + gl * 8]     = make_float4(v[0], v[1], v[2], v[3]);
        *(float4*)&out[(size_t)node * C + gl * 8 + 4] = make_float4(v[4], v[5], v[6], v[7]);
    }
}

static inline size_t align_up(size_t x) { return (x + 255) & ~(size_t)255; }

extern "C" void kernel_launch(void* const* d_in, const int* in_sizes, int n_in,
                              void* d_out, int out_size, void* d_ws, size_t ws_size,
                              hipStream_t stream) {
    const float* x   = (const float*)d_in[0];
    const int*  eidx = (const int*)d_in[1];
    const float* W1  = (const float*)d_in[2];
    const float* b1  = (const float*)d_in[3];
    const float* W2  = (const float*)d_in[4];
    const float* b2  = (const float*)d_in[5];
    const float* W3  = (const float*)d_in[6];
    const float* b3  = (const float*)d_in[7];
    float* out = (float*)d_out;

    const int N = in_sizes[0] / 128;   // 50000 (< 65536 required for packing)
    const int E = in_sizes[1] / 2;     // 800000
    const int* srcp = eidx;
    const int* dstp = eidx + E;
    const int nbuckets = (N + 255) >> 8;   // 196

    char* ws = (char*)d_ws;
    size_t o = 0;
    float* dis   = (float*)(ws + o);  o = align_up(o + (size_t)N * 4);
    int* off     = (int*)(ws + o);    o = align_up(o + (size_t)(N + 1) * 4);
    int* btot    = (int*)(ws + o);    o = align_up(o + 256 * 4);
    int* bbase   = (int*)(ws + o);    o = align_up(o + 257 * 4);
    int* hist    = (int*)(ws + o);    o = align_up(o + 256 * 256 * 4);
    int* bedge   = (int*)(ws + o);    o = align_up(o + (size_t)E * 4);
    int* csr     = (int*)(ws + o);    o = align_up(o + (size_t)E * 4);
    float* A     = (float*)(ws + o);  o = align_up(o + (size_t)N * 64 * 4);
    __half* H    = (__half*)(ws + o); o = align_up(o + (size_t)N * 64 * 2);

    const dim3 blk(256);

    // --- CSR build (no global atomics) ---
    part_hist_kernel<<<dim3(256), blk, 0, stream>>>(dstp, hist, E, nbuckets);
    part_scan_kernel<<<dim3(nbuckets), blk, 0, stream>>>(hist, btot);
    bucket_base_kernel<<<dim3(1), blk, 0, stream>>>(btot, bbase, nbuckets);
    part_scatter_kernel<<<dim3(256), blk, 0, stream>>>(srcp, dstp, hist, bbase, bedge, E, nbuckets);
    bucket_csr_kernel<<<dim3(nbuckets), blk, 0, stream>>>(bedge, bbase, csr, off, dis, N);

    const int agg_blocks = (N + 3) / 4;
    // rows per block: R = (256/(C/4)) * TR
    const int g64 = (N + 31) / 32;   // C=64, TR=2 -> R=32
    const int g32 = (N + 63) / 64;   // C=32, TR=2 -> R=64

    // --- layer 1: x[128] @ W1 -> H (fp16); agg -> A (relu + b1) ---
    gemm_scale_kernel<128, 64, 2><<<dim3(g64), blk, 0, stream>>>(x, W1, dis, H, N);
    agg_kernel<64, true><<<dim3(agg_blocks), blk, 0, stream>>>(off, csr, dis, H, b1, A, N);

    // --- layer 2: A[64] @ W2 -> H (fp16); agg -> A (relu + b2) ---
    gemm_scale_kernel<64, 64, 2><<<dim3(g64), blk, 0, stream>>>(A, W2, dis, H, N);
    agg_kernel<64, true><<<dim3(agg_blocks), blk, 0, stream>>>(off, csr, dis, H, b2, A, N);

    // --- layer 3: A[64] @ W3 -> H (fp16, 32ch); agg -> out (+b3, no relu) ---
    gemm_scale_kernel<64, 32, 2><<<dim3(g32), blk, 0, stream>>>(A, W3, dis, H, N);
    agg_kernel<32, false><<<dim3(agg_blocks), blk, 0, stream>>>(off, csr, dis, H, b3, out, N);
}